// Round 2
// baseline (156.812 us; speedup 1.0000x reference)
//
#include <hip/hip_runtime.h>
#include <stdint.h>

typedef unsigned short u16;
typedef __attribute__((ext_vector_type(8))) short bf16x8;
typedef __attribute__((ext_vector_type(4))) float f32x4;

#define NTOK 1024      // H*W
#define DMODEL 256
#define NHEAD 8
#define DK 32
#define NBATCH 8
#define PER_B (DMODEL * NTOK)   // 262144

__device__ __forceinline__ float b2f(u16 h) {
    union { unsigned u; float f; } c; c.u = ((unsigned)h) << 16; return c.f;
}
__device__ __forceinline__ u16 f2b(float f) {
    unsigned u = __float_as_uint(f);
    unsigned r = u + 0x7fffu + ((u >> 16) & 1u);
    return (u16)(r >> 16);
}

// ---------------- Kernel 1: LN partial sums (deterministic, no atomics) ----------------
// grid (8 b, 8 slices), block 256. Each block: 32768 floats.
__global__ void ln_partial(const float* __restrict__ x, float* __restrict__ part) {
    int b = blockIdx.x, sl = blockIdx.y;
    int t = threadIdx.x;
    int w = t >> 6, l = t & 63;
    const float* xb = x + (size_t)b * PER_B + sl * (PER_B / 8);
    float s = 0.f, ss = 0.f;
    for (int base = 0; base < PER_B / 8; base += 1024) {
        float4 v = *(const float4*)&xb[base + t * 4];
        s += v.x + v.y + v.z + v.w;
        ss += v.x * v.x + v.y * v.y + v.z * v.z + v.w * v.w;
    }
    for (int d = 1; d < 64; d <<= 1) {
        s += __shfl_xor(s, d, 64);
        ss += __shfl_xor(ss, d, 64);
    }
    __shared__ float red[2][4];
    if (l == 0) { red[0][w] = s; red[1][w] = ss; }
    __syncthreads();
    if (t == 0) {
        float S = red[0][0] + red[0][1] + red[0][2] + red[0][3];
        float SS = red[1][0] + red[1][1] + red[1][2] + red[1][3];
        part[(b * 8 + sl) * 2] = S;
        part[(b * 8 + sl) * 2 + 1] = SS;
    }
}

// ---------------- Kernel 2: weights fp32 -> bf16 ----------------
// wb layout: [4][256*256]  (q, k, v, o); grid (64, 4), block 256, 4 elems/thread
__global__ void cvt_w(const float* __restrict__ Wq, const float* __restrict__ Wk,
                      const float* __restrict__ Wv, const float* __restrict__ Wo,
                      u16* __restrict__ wb) {
    int m = blockIdx.y;
    const float* W = (m == 0) ? Wq : (m == 1) ? Wk : (m == 2) ? Wv : Wo;
    int i = (blockIdx.x * 256 + threadIdx.x) * 4;
    float4 v = *(const float4*)&W[i];
    ushort4 o;
    o.x = f2b(v.x); o.y = f2b(v.y); o.z = f2b(v.z); o.w = f2b(v.w);
    *(ushort4*)&wb[m * 65536 + i] = o;
}

// ---------------- Kernel 3: normalize + transpose [c,n] -> [n,c], fp32 -> bf16 ----------------
__global__ void normT(const float* __restrict__ x, const float* __restrict__ part,
                      u16* __restrict__ xn) {
    int b = blockIdx.z;
    int n0 = blockIdx.x * 32;
    int c0 = blockIdx.y * 32;
    int tx = threadIdx.x, ty = threadIdx.y;   // (32, 8)
    __shared__ float s_mu, s_rs;
    __shared__ float tile[32][33];
    if (tx == 0 && ty == 0) {
        float S = 0.f, SS = 0.f;
        for (int i = 0; i < 8; ++i) { S += part[(b * 8 + i) * 2]; SS += part[(b * 8 + i) * 2 + 1]; }
        float mu = S / (float)PER_B;
        float var = SS / (float)PER_B - mu * mu;
        s_mu = mu;
        s_rs = rsqrtf(var + 1e-5f);
    }
    __syncthreads();
    float mu = s_mu, rs = s_rs;
    const float* xb = x + (size_t)b * PER_B;
#pragma unroll
    for (int i = 0; i < 4; ++i) {
        int c = c0 + ty + i * 8;
        tile[ty + i * 8][tx] = (xb[c * NTOK + n0 + tx] - mu) * rs;
    }
    __syncthreads();
    u16* xnb = xn + (size_t)b * PER_B;
#pragma unroll
    for (int i = 0; i < 4; ++i) {
        int n = n0 + ty + i * 8;
        xnb[n * DMODEL + c0 + tx] = f2b(tile[tx][ty + i * 8]);
    }
}

// ---------------- Kernel 4: QKV projection GEMM (MFMA bf16) ----------------
// grid (16 m-tiles, 12 o-tiles, 8 b); block 256 = 4 waves; tile 64x64, K=256 in 8 steps
__global__ __launch_bounds__(256) void qkv_gemm(
    const u16* __restrict__ xn, const u16* __restrict__ wb,
    const float* __restrict__ bq, const float* __restrict__ bk,
    const float* __restrict__ bv,
    u16* __restrict__ qo, u16* __restrict__ ko, u16* __restrict__ vo) {
    int mt = blockIdx.x;
    int ot = blockIdx.y;
    int b = blockIdx.z;
    int sel = ot >> 2;            // 0=q 1=k 2=v
    int o0 = (ot & 3) * 64;       // within [0,256)
    const u16* W = wb + sel * 65536;
    const float* bias = (sel == 0) ? bq : (sel == 1) ? bk : bv;
    u16* outp = (sel == 0) ? qo : (sel == 1) ? ko : vo;

    __shared__ u16 As[64][40];
    __shared__ u16 Bs[64][40];
    int t = threadIdx.x;
    int w = t >> 6, l = t & 63;
    int lr = t >> 2;              // staging row 0..63
    int lc = (t & 3) * 8;         // 0,8,16,24
    int qd = l >> 4, ln = l & 15;

    const u16* xb = xn + ((size_t)b * NTOK + mt * 64) * DMODEL;
    f32x4 acc[4] = {};
    for (int kb = 0; kb < 8; ++kb) {
        *(uint4*)&As[lr][lc] = *(const uint4*)&xb[lr * DMODEL + kb * 32 + lc];
        *(uint4*)&Bs[lr][lc] = *(const uint4*)&W[(o0 + lr) * DMODEL + kb * 32 + lc];
        __syncthreads();
        bf16x8 af = *(const bf16x8*)&As[w * 16 + ln][qd * 8];
#pragma unroll
        for (int ns = 0; ns < 4; ++ns) {
            bf16x8 bf = *(const bf16x8*)&Bs[ns * 16 + ln][qd * 8];
            acc[ns] = __builtin_amdgcn_mfma_f32_16x16x32_bf16(af, bf, acc[ns], 0, 0, 0);
        }
        __syncthreads();
    }
    float scale = (sel == 0) ? 0.17677669529663687f : 1.0f;  // DK^-0.5 folded into q
#pragma unroll
    for (int ns = 0; ns < 4; ++ns) {
        int o = o0 + ns * 16 + ln;          // 0..255
        float bias_f = bias[o];
        int head = o >> 5, d = o & 31;
#pragma unroll
        for (int r = 0; r < 4; ++r) {
            int n_row = mt * 64 + w * 16 + qd * 4 + r;
            float v = (acc[ns][r] + bias_f) * scale;
            outp[(((size_t)b * NHEAD + head) * NTOK + n_row) * DK + d] = f2b(v);
        }
    }
}

// ---------------- Kernel 5: flash attention per 64-query tile ----------------
// grid (16 q-tiles, 64 b*h); block 256 = 4 waves; each wave owns 16 q rows
__global__ __launch_bounds__(256) void attn(
    const u16* __restrict__ qws, const u16* __restrict__ kws,
    const u16* __restrict__ vws, u16* __restrict__ tmp) {
    int qt = blockIdx.x;
    int bh = blockIdx.y;
    int b = bh >> 3, h = bh & 7;
    const u16* Q = qws + (size_t)bh * NTOK * DK;
    const u16* K = kws + (size_t)bh * NTOK * DK;
    const u16* V = vws + (size_t)bh * NTOK * DK;

    __shared__ u16 Qs[64][40];
    __shared__ u16 Ks[64][40];
    __shared__ u16 Vt[32][72];   // V transposed: [dv][key]
    __shared__ u16 Ps[64][72];   // P: [q][key]

    int t = threadIdx.x;
    int w = t >> 6, l = t & 63;
    int lr = t >> 2;             // 0..63
    int lc = (t & 3) * 8;        // 0,8,16,24
    int qd = l >> 4, ln = l & 15;

    *(uint4*)&Qs[lr][lc] = *(const uint4*)&Q[(qt * 64 + lr) * DK + lc];
    __syncthreads();
    bf16x8 qf = *(const bf16x8*)&Qs[w * 16 + ln][qd * 8];

    float m_r[4], l_r[4];
    f32x4 oacc[2] = {};
#pragma unroll
    for (int r = 0; r < 4; ++r) { m_r[r] = -1e30f; l_r[r] = 0.f; }

    for (int kt = 0; kt < 16; ++kt) {
        *(uint4*)&Ks[lr][lc] = *(const uint4*)&K[(kt * 64 + lr) * DK + lc];
        {
            u16 vtmp[8];
            *(uint4*)vtmp = *(const uint4*)&V[(kt * 64 + lr) * DK + lc];
#pragma unroll
            for (int j = 0; j < 8; ++j) Vt[lc + j][lr] = vtmp[j];
        }
        __syncthreads();
        // S = Q K^T (q pre-scaled)
        f32x4 s[4];
#pragma unroll
        for (int ns = 0; ns < 4; ++ns) {
            bf16x8 kf = *(const bf16x8*)&Ks[ns * 16 + ln][qd * 8];
            f32x4 z = {0.f, 0.f, 0.f, 0.f};
            s[ns] = __builtin_amdgcn_mfma_f32_16x16x32_bf16(qf, kf, z, 0, 0, 0);
        }
        // online softmax; wave's C-layout rows: row = qd*4+r
#pragma unroll
        for (int r = 0; r < 4; ++r) {
            float tm = fmaxf(fmaxf(s[0][r], s[1][r]), fmaxf(s[2][r], s[3][r]));
#pragma unroll
            for (int d = 1; d < 16; d <<= 1) tm = fmaxf(tm, __shfl_xor(tm, d, 64));
            float mn = fmaxf(m_r[r], tm);
            float alpha = __expf(m_r[r] - mn);
            float rs = 0.f;
#pragma unroll
            for (int ns = 0; ns < 4; ++ns) {
                float p = __expf(s[ns][r] - mn);
                rs += p;
                Ps[w * 16 + qd * 4 + r][ns * 16 + ln] = f2b(p);
            }
#pragma unroll
            for (int d = 1; d < 16; d <<= 1) rs += __shfl_xor(rs, d, 64);
            l_r[r] = l_r[r] * alpha + rs;
            m_r[r] = mn;
            oacc[0][r] *= alpha;
            oacc[1][r] *= alpha;
        }
        // O += P V  (P read back in A-layout; same-wave LDS rows only)
#pragma unroll
        for (int kh = 0; kh < 2; ++kh) {
            bf16x8 pf = *(const bf16x8*)&Ps[w * 16 + ln][kh * 32 + qd * 8];
#pragma unroll
            for (int ns = 0; ns < 2; ++ns) {
                bf16x8 vf = *(const bf16x8*)&Vt[ns * 16 + ln][kh * 32 + qd * 8];
                oacc[ns] = __builtin_amdgcn_mfma_f32_16x16x32_bf16(pf, vf, oacc[ns], 0, 0, 0);
            }
        }
        __syncthreads();
    }
    // epilogue: tmp[b][n][h*32 + d]
#pragma unroll
    for (int ns = 0; ns < 2; ++ns) {
#pragma unroll
        for (int r = 0; r < 4; ++r) {
            int n_row = qt * 64 + w * 16 + qd * 4 + r;
            float v = oacc[ns][r] / l_r[r];
            tmp[((size_t)b * NTOK + n_row) * DMODEL + h * DK + ns * 16 + ln] = f2b(v);
        }
    }
}

// ---------------- Kernel 6: output projection + bias + residual (fp32 out) ----------------
// grid (16 m-tiles, 4 o-tiles, 8 b); raw-reshape residual: flat f = n*256 + d
__global__ __launch_bounds__(256) void oproj(
    const u16* __restrict__ tmp, const u16* __restrict__ wb,
    const float* __restrict__ bo, const float* __restrict__ x,
    float* __restrict__ out) {
    int mt = blockIdx.x;
    int ot = blockIdx.y;
    int b = blockIdx.z;
    const u16* Wo = wb + 3 * 65536;

    __shared__ u16 As[64][40];
    __shared__ u16 Bs[64][40];
    int t = threadIdx.x;
    int w = t >> 6, l = t & 63;
    int lr = t >> 2;
    int lc = (t & 3) * 8;
    int qd = l >> 4, ln = l & 15;

    const u16* ab = tmp + ((size_t)b * NTOK + mt * 64) * DMODEL;
    f32x4 acc[4] = {};
    for (int kb = 0; kb < 8; ++kb) {
        *(uint4*)&As[lr][lc] = *(const uint4*)&ab[lr * DMODEL + kb * 32 + lc];
        *(uint4*)&Bs[lr][lc] = *(const uint4*)&Wo[(ot * 64 + lr) * DMODEL + kb * 32 + lc];
        __syncthreads();
        bf16x8 af = *(const bf16x8*)&As[w * 16 + ln][qd * 8];
#pragma unroll
        for (int ns = 0; ns < 4; ++ns) {
            bf16x8 bf = *(const bf16x8*)&Bs[ns * 16 + ln][qd * 8];
            acc[ns] = __builtin_amdgcn_mfma_f32_16x16x32_bf16(af, bf, acc[ns], 0, 0, 0);
        }
        __syncthreads();
    }
    const float* xb = x + (size_t)b * PER_B;
    float* ob = out + (size_t)b * PER_B;
#pragma unroll
    for (int ns = 0; ns < 4; ++ns) {
        int o = ot * 64 + ns * 16 + ln;   // 0..255
        float bias_f = bo[o];
#pragma unroll
        for (int r = 0; r < 4; ++r) {
            int n_row = mt * 64 + w * 16 + qd * 4 + r;
            size_t idx = (size_t)n_row * DMODEL + o;
            ob[idx] = acc[ns][r] + bias_f + xb[idx];
        }
    }
}

extern "C" void kernel_launch(void* const* d_in, const int* in_sizes, int n_in,
                              void* d_out, int out_size, void* d_ws, size_t ws_size,
                              hipStream_t stream) {
    const float* x  = (const float*)d_in[0];
    const float* Wq = (const float*)d_in[1];
    const float* bq = (const float*)d_in[2];
    const float* Wk = (const float*)d_in[3];
    const float* bk = (const float*)d_in[4];
    const float* Wv = (const float*)d_in[5];
    const float* bv = (const float*)d_in[6];
    const float* Wo = (const float*)d_in[7];
    const float* bo = (const float*)d_in[8];
    float* out = (float*)d_out;

    char* ws = (char*)d_ws;
    float* part = (float*)ws;                          // 128 floats = 512 B (use 1 KB)
    u16* wb  = (u16*)(ws + 1024);                      // 512 KB (4 x 256x256 bf16)
    u16* xn  = (u16*)(ws + 1024 + (512u << 10));       // 4 MB (reused as attn output tmp)
    u16* qws = (u16*)(ws + 1024 + (512u << 10) + (4u << 20));
    u16* kws = (u16*)(ws + 1024 + (512u << 10) + (8u << 20));
    u16* vws = (u16*)(ws + 1024 + (512u << 10) + (12u << 20));
    u16* tmp = xn;                                     // xn dead after qkv_gemm

    hipLaunchKernelGGL(ln_partial, dim3(8, 8), dim3(256), 0, stream, x, part);
    hipLaunchKernelGGL(cvt_w, dim3(64, 4), dim3(256), 0, stream, Wq, Wk, Wv, Wo, wb);
    hipLaunchKernelGGL(normT, dim3(32, 8, 8), dim3(32, 8), 0, stream, x, part, xn);
    hipLaunchKernelGGL(qkv_gemm, dim3(16, 12, 8), dim3(256), 0, stream,
                       xn, wb, bq, bk, bv, qws, kws, vws);
    hipLaunchKernelGGL(attn, dim3(16, 64), dim3(256), 0, stream, qws, kws, vws, tmp);
    hipLaunchKernelGGL(oproj, dim3(16, 4, 8), dim3(256), 0, stream, tmp, wb, bo, x, out);
}

// Round 3
// 147.191 us; speedup vs baseline: 1.0654x; 1.0654x over previous
//
#include <hip/hip_runtime.h>
#include <stdint.h>

typedef unsigned short u16;
typedef __attribute__((ext_vector_type(8))) short bf16x8;
typedef __attribute__((ext_vector_type(4))) float f32x4;

#define NTOK 1024      // H*W
#define DMODEL 256
#define NHEAD 8
#define DK 32
#define NBATCH 8
#define PER_B (DMODEL * NTOK)   // 262144

__device__ __forceinline__ float b2f(u16 h) {
    union { unsigned u; float f; } c; c.u = ((unsigned)h) << 16; return c.f;
}
__device__ __forceinline__ u16 f2b(float f) {
    unsigned u = __float_as_uint(f);
    unsigned r = u + 0x7fffu + ((u >> 16) & 1u);
    return (u16)(r >> 16);
}

// ---------------- Kernel 1: LN partial sums (deterministic, no atomics) ----------------
__global__ void ln_partial(const float* __restrict__ x, float* __restrict__ part) {
    int b = blockIdx.x, sl = blockIdx.y;
    int t = threadIdx.x;
    int w = t >> 6, l = t & 63;
    const float* xb = x + (size_t)b * PER_B + sl * (PER_B / 8);
    float s = 0.f, ss = 0.f;
    for (int base = 0; base < PER_B / 8; base += 1024) {
        float4 v = *(const float4*)&xb[base + t * 4];
        s += v.x + v.y + v.z + v.w;
        ss += v.x * v.x + v.y * v.y + v.z * v.z + v.w * v.w;
    }
    for (int d = 1; d < 64; d <<= 1) {
        s += __shfl_xor(s, d, 64);
        ss += __shfl_xor(ss, d, 64);
    }
    __shared__ float red[2][4];
    if (l == 0) { red[0][w] = s; red[1][w] = ss; }
    __syncthreads();
    if (t == 0) {
        float S = red[0][0] + red[0][1] + red[0][2] + red[0][3];
        float SS = red[1][0] + red[1][1] + red[1][2] + red[1][3];
        part[(b * 8 + sl) * 2] = S;
        part[(b * 8 + sl) * 2 + 1] = SS;
    }
}

// ---------------- Kernel 2: weights fp32 -> bf16 ----------------
__global__ void cvt_w(const float* __restrict__ Wq, const float* __restrict__ Wk,
                      const float* __restrict__ Wv, const float* __restrict__ Wo,
                      u16* __restrict__ wb) {
    int m = blockIdx.y;
    const float* W = (m == 0) ? Wq : (m == 1) ? Wk : (m == 2) ? Wv : Wo;
    int i = (blockIdx.x * 256 + threadIdx.x) * 4;
    float4 v = *(const float4*)&W[i];
    ushort4 o;
    o.x = f2b(v.x); o.y = f2b(v.y); o.z = f2b(v.z); o.w = f2b(v.w);
    *(ushort4*)&wb[m * 65536 + i] = o;
}

// ---------------- Kernel 3: normalize + transpose [c,n] -> [n,c], fp32 -> bf16 ----------------
__global__ void normT(const float* __restrict__ x, const float* __restrict__ part,
                      u16* __restrict__ xn) {
    int b = blockIdx.z;
    int n0 = blockIdx.x * 32;
    int c0 = blockIdx.y * 32;
    int tx = threadIdx.x, ty = threadIdx.y;   // (32, 8)
    __shared__ float s_mu, s_rs;
    __shared__ float tile[32][33];
    if (tx == 0 && ty == 0) {
        float S = 0.f, SS = 0.f;
        for (int i = 0; i < 8; ++i) { S += part[(b * 8 + i) * 2]; SS += part[(b * 8 + i) * 2 + 1]; }
        float mu = S / (float)PER_B;
        float var = SS / (float)PER_B - mu * mu;
        s_mu = mu;
        s_rs = rsqrtf(var + 1e-5f);
    }
    __syncthreads();
    float mu = s_mu, rs = s_rs;
    const float* xb = x + (size_t)b * PER_B;
#pragma unroll
    for (int i = 0; i < 4; ++i) {
        int c = c0 + ty + i * 8;
        tile[ty + i * 8][tx] = (xb[c * NTOK + n0 + tx] - mu) * rs;
    }
    __syncthreads();
    u16* xnb = xn + (size_t)b * PER_B;
#pragma unroll
    for (int i = 0; i < 4; ++i) {
        int n = n0 + ty + i * 8;
        xnb[n * DMODEL + c0 + tx] = f2b(tile[tx][ty + i * 8]);
    }
}

// ---------------- Kernel 4: QKV projection GEMM (MFMA bf16) ----------------
// grid (16 m-tiles, 12 o-tiles, 8 b); block 256 = 4 waves; tile 64x64, K=256 in 8 steps
// q,k outputs: [bh][n][32];  v output: TRANSPOSED [bh][dv][n] for attn's direct vf loads
__global__ __launch_bounds__(256) void qkv_gemm(
    const u16* __restrict__ xn, const u16* __restrict__ wb,
    const float* __restrict__ bq, const float* __restrict__ bk,
    const float* __restrict__ bv,
    u16* __restrict__ qo, u16* __restrict__ ko, u16* __restrict__ vo) {
    int mt = blockIdx.x;
    int ot = blockIdx.y;
    int b = blockIdx.z;
    int sel = ot >> 2;            // 0=q 1=k 2=v
    int o0 = (ot & 3) * 64;       // within [0,256)
    const u16* W = wb + sel * 65536;
    const float* bias = (sel == 0) ? bq : (sel == 1) ? bk : bv;

    __shared__ u16 As[64][40];
    __shared__ u16 Bs[64][40];
    int t = threadIdx.x;
    int w = t >> 6, l = t & 63;
    int lr = t >> 2;              // staging row 0..63
    int lc = (t & 3) * 8;         // 0,8,16,24
    int qd = l >> 4, ln = l & 15;

    const u16* xb = xn + ((size_t)b * NTOK + mt * 64) * DMODEL;
    f32x4 acc[4] = {};
    for (int kb = 0; kb < 8; ++kb) {
        *(uint4*)&As[lr][lc] = *(const uint4*)&xb[lr * DMODEL + kb * 32 + lc];
        *(uint4*)&Bs[lr][lc] = *(const uint4*)&W[(o0 + lr) * DMODEL + kb * 32 + lc];
        __syncthreads();
        bf16x8 af = *(const bf16x8*)&As[w * 16 + ln][qd * 8];
#pragma unroll
        for (int ns = 0; ns < 4; ++ns) {
            bf16x8 bf = *(const bf16x8*)&Bs[ns * 16 + ln][qd * 8];
            acc[ns] = __builtin_amdgcn_mfma_f32_16x16x32_bf16(af, bf, acc[ns], 0, 0, 0);
        }
        __syncthreads();
    }
    if (sel < 2) {
        u16* outp = (sel == 0) ? qo : ko;
        float scale = (sel == 0) ? 0.17677669529663687f : 1.0f;  // DK^-0.5 folded into q
#pragma unroll
        for (int ns = 0; ns < 4; ++ns) {
            int o = o0 + ns * 16 + ln;          // 0..255
            float bias_f = bias[o];
            int head = o >> 5, d = o & 31;
#pragma unroll
            for (int r = 0; r < 4; ++r) {
                int n_row = mt * 64 + w * 16 + qd * 4 + r;
                float v = (acc[ns][r] + bias_f) * scale;
                outp[(((size_t)b * NHEAD + head) * NTOK + n_row) * DK + d] = f2b(v);
            }
        }
    } else {
        // V transposed: vo[bh][dv][n]; lane owns 4 consecutive n -> packed ushort4
        int n0 = mt * 64 + w * 16 + qd * 4;
#pragma unroll
        for (int ns = 0; ns < 4; ++ns) {
            int o = o0 + ns * 16 + ln;          // 0..255
            float bias_f = bias[o];
            int head = o >> 5, d = o & 31;
            ushort4 pk;
            pk.x = f2b(acc[ns][0] + bias_f);
            pk.y = f2b(acc[ns][1] + bias_f);
            pk.z = f2b(acc[ns][2] + bias_f);
            pk.w = f2b(acc[ns][3] + bias_f);
            *(ushort4*)&vo[(((size_t)b * NHEAD + head) * DK + d) * NTOK + n0] = pk;
        }
    }
}

// ---------------- Kernel 5: attention, no-max softmax, zero barriers ----------------
// grid (16 q-tiles, 64 b*h); block 256 = 4 waves; each wave owns 16 q rows, fully independent.
// Q,K: [bh][n][32] global direct loads; Vt: [bh][dv][n] global direct loads.
// LDS: only P, per-wave 16x80 bf16 region, 16B-chunk XOR(q>>2) swizzle -> conflict-free.
__global__ __launch_bounds__(256) void attn(
    const u16* __restrict__ qws, const u16* __restrict__ kws,
    const u16* __restrict__ vtws, u16* __restrict__ tmp) {
    int qt = blockIdx.x;
    int bh = blockIdx.y;
    int b = bh >> 3, h = bh & 7;
    const u16* Q  = qws  + (size_t)bh * NTOK * DK;
    const u16* K  = kws  + (size_t)bh * NTOK * DK;
    const u16* Vt = vtws + (size_t)bh * DK * NTOK;   // [dv][n]

    __shared__ u16 Ps[4][16 * 80];   // per-wave P tile

    int t = threadIdx.x;
    int w = t >> 6, l = t & 63;
    int qd = l >> 4, ln = l & 15;
    u16* psw = &Ps[w][0];

    // Q fragment: rows q = qt*64 + w*16 + ln, k = qd*8..+7 (coalesced 16B)
    bf16x8 qf = *(const bf16x8*)&Q[(qt * 64 + w * 16 + ln) * DK + qd * 8];

    // Precomputed LDS addresses (loop-invariant).
    // write: row q_local=qd*4+r (via +80*r), chunk c = 2*ns+(ln>>3), stored at c^qd
    int wbase[4];
#pragma unroll
    for (int ns = 0; ns < 4; ++ns)
        wbase[ns] = (qd * 4) * 80 + ((2 * ns + (ln >> 3)) ^ qd) * 8 + (ln & 7);
    // read: row q_local=ln, chunk c = kh*4+qd, stored at c^(ln>>2)
    const bf16x8* rb[2];
#pragma unroll
    for (int kh = 0; kh < 2; ++kh)
        rb[kh] = (const bf16x8*)&psw[ln * 80 + (((kh * 4 + qd) ^ (ln >> 2)) * 8)];

    float lsum[4] = {0.f, 0.f, 0.f, 0.f};
    f32x4 oacc[2] = {};

    for (int kt = 0; kt < 16; ++kt) {
        // K fragments: key rows kt*64 + ns*16 + ln
        bf16x8 kf0 = *(const bf16x8*)&K[(kt * 64 +  0 + ln) * DK + qd * 8];
        bf16x8 kf1 = *(const bf16x8*)&K[(kt * 64 + 16 + ln) * DK + qd * 8];
        bf16x8 kf2 = *(const bf16x8*)&K[(kt * 64 + 32 + ln) * DK + qd * 8];
        bf16x8 kf3 = *(const bf16x8*)&K[(kt * 64 + 48 + ln) * DK + qd * 8];
        // V fragments: rows dv = ns*16+ln, k = kt*64 + kh*32 + qd*8
        bf16x8 vf00 = *(const bf16x8*)&Vt[( 0 + ln) * NTOK + kt * 64 +  0 + qd * 8];
        bf16x8 vf01 = *(const bf16x8*)&Vt[( 0 + ln) * NTOK + kt * 64 + 32 + qd * 8];
        bf16x8 vf10 = *(const bf16x8*)&Vt[(16 + ln) * NTOK + kt * 64 +  0 + qd * 8];
        bf16x8 vf11 = *(const bf16x8*)&Vt[(16 + ln) * NTOK + kt * 64 + 32 + qd * 8];

        f32x4 s[4];
        f32x4 z = {0.f, 0.f, 0.f, 0.f};
        s[0] = __builtin_amdgcn_mfma_f32_16x16x32_bf16(qf, kf0, z, 0, 0, 0);
        s[1] = __builtin_amdgcn_mfma_f32_16x16x32_bf16(qf, kf1, z, 0, 0, 0);
        s[2] = __builtin_amdgcn_mfma_f32_16x16x32_bf16(qf, kf2, z, 0, 0, 0);
        s[3] = __builtin_amdgcn_mfma_f32_16x16x32_bf16(qf, kf3, z, 0, 0, 0);

        // p = exp(s); accumulate l; store bf16 P (swizzled, conflict-free)
#pragma unroll
        for (int ns = 0; ns < 4; ++ns) {
#pragma unroll
            for (int r = 0; r < 4; ++r) {
                float p = __expf(s[ns][r]);
                lsum[r] += p;
                psw[wbase[ns] + r * 80] = f2b(p);
            }
        }
        // O += P V
        bf16x8 pf0 = *rb[0];
        bf16x8 pf1 = *rb[1];
        oacc[0] = __builtin_amdgcn_mfma_f32_16x16x32_bf16(pf0, vf00, oacc[0], 0, 0, 0);
        oacc[0] = __builtin_amdgcn_mfma_f32_16x16x32_bf16(pf1, vf01, oacc[0], 0, 0, 0);
        oacc[1] = __builtin_amdgcn_mfma_f32_16x16x32_bf16(pf0, vf10, oacc[1], 0, 0, 0);
        oacc[1] = __builtin_amdgcn_mfma_f32_16x16x32_bf16(pf1, vf11, oacc[1], 0, 0, 0);
    }

    // final l reduction across the 16 k-columns (lanes ln)
    float linv[4];
#pragma unroll
    for (int r = 0; r < 4; ++r) {
        float s = lsum[r];
        s += __shfl_xor(s, 1, 64);
        s += __shfl_xor(s, 2, 64);
        s += __shfl_xor(s, 4, 64);
        s += __shfl_xor(s, 8, 64);
        linv[r] = 1.0f / s;
    }
    // epilogue: tmp[b][n][h*32 + dv]
#pragma unroll
    for (int ns = 0; ns < 2; ++ns) {
#pragma unroll
        for (int r = 0; r < 4; ++r) {
            int n_row = qt * 64 + w * 16 + qd * 4 + r;
            float v = oacc[ns][r] * linv[r];
            tmp[((size_t)b * NTOK + n_row) * DMODEL + h * DK + ns * 16 + ln] = f2b(v);
        }
    }
}

// ---------------- Kernel 6: output projection + bias + residual (fp32 out) ----------------
__global__ __launch_bounds__(256) void oproj(
    const u16* __restrict__ tmp, const u16* __restrict__ wb,
    const float* __restrict__ bo, const float* __restrict__ x,
    float* __restrict__ out) {
    int mt = blockIdx.x;
    int ot = blockIdx.y;
    int b = blockIdx.z;
    const u16* Wo = wb + 3 * 65536;

    __shared__ u16 As[64][40];
    __shared__ u16 Bs[64][40];
    int t = threadIdx.x;
    int w = t >> 6, l = t & 63;
    int lr = t >> 2;
    int lc = (t & 3) * 8;
    int qd = l >> 4, ln = l & 15;

    const u16* ab = tmp + ((size_t)b * NTOK + mt * 64) * DMODEL;
    f32x4 acc[4] = {};
    for (int kb = 0; kb < 8; ++kb) {
        *(uint4*)&As[lr][lc] = *(const uint4*)&ab[lr * DMODEL + kb * 32 + lc];
        *(uint4*)&Bs[lr][lc] = *(const uint4*)&Wo[(ot * 64 + lr) * DMODEL + kb * 32 + lc];
        __syncthreads();
        bf16x8 af = *(const bf16x8*)&As[w * 16 + ln][qd * 8];
#pragma unroll
        for (int ns = 0; ns < 4; ++ns) {
            bf16x8 bf = *(const bf16x8*)&Bs[ns * 16 + ln][qd * 8];
            acc[ns] = __builtin_amdgcn_mfma_f32_16x16x32_bf16(af, bf, acc[ns], 0, 0, 0);
        }
        __syncthreads();
    }
    const float* xb = x + (size_t)b * PER_B;
    float* ob = out + (size_t)b * PER_B;
#pragma unroll
    for (int ns = 0; ns < 4; ++ns) {
        int o = ot * 64 + ns * 16 + ln;   // 0..255
        float bias_f = bo[o];
#pragma unroll
        for (int r = 0; r < 4; ++r) {
            int n_row = mt * 64 + w * 16 + qd * 4 + r;
            size_t idx = (size_t)n_row * DMODEL + o;
            ob[idx] = acc[ns][r] + bias_f + xb[idx];
        }
    }
}

extern "C" void kernel_launch(void* const* d_in, const int* in_sizes, int n_in,
                              void* d_out, int out_size, void* d_ws, size_t ws_size,
                              hipStream_t stream) {
    const float* x  = (const float*)d_in[0];
    const float* Wq = (const float*)d_in[1];
    const float* bq = (const float*)d_in[2];
    const float* Wk = (const float*)d_in[3];
    const float* bk = (const float*)d_in[4];
    const float* Wv = (const float*)d_in[5];
    const float* bv = (const float*)d_in[6];
    const float* Wo = (const float*)d_in[7];
    const float* bo = (const float*)d_in[8];
    float* out = (float*)d_out;

    char* ws = (char*)d_ws;
    float* part = (float*)ws;                          // 1 KB
    u16* wb  = (u16*)(ws + 1024);                      // 512 KB (4 x 256x256 bf16)
    u16* xn  = (u16*)(ws + 1024 + (512u << 10));       // 4 MB (reused as attn output tmp)
    u16* qws = (u16*)(ws + 1024 + (512u << 10) + (4u << 20));
    u16* kws = (u16*)(ws + 1024 + (512u << 10) + (8u << 20));
    u16* vws = (u16*)(ws + 1024 + (512u << 10) + (12u << 20));  // transposed [bh][dv][n]
    u16* tmp = xn;                                     // xn dead after qkv_gemm

    hipLaunchKernelGGL(ln_partial, dim3(8, 8), dim3(256), 0, stream, x, part);
    hipLaunchKernelGGL(cvt_w, dim3(64, 4), dim3(256), 0, stream, Wq, Wk, Wv, Wo, wb);
    hipLaunchKernelGGL(normT, dim3(32, 8, 8), dim3(32, 8), 0, stream, x, part, xn);
    hipLaunchKernelGGL(qkv_gemm, dim3(16, 12, 8), dim3(256), 0, stream,
                       xn, wb, bq, bk, bv, qws, kws, vws);
    hipLaunchKernelGGL(attn, dim3(16, 64), dim3(256), 0, stream, qws, kws, vws, tmp);
    hipLaunchKernelGGL(oproj, dim3(16, 4, 8), dim3(256), 0, stream, tmp, wb, bo, x, out);
}